// Round 1
// baseline (4449.474 us; speedup 1.0000x reference)
//
#include <hip/hip_runtime.h>
#include <hip/hip_bf16.h>

#define B_ 4
#define S_ 1024
#define D_ 1024
#define H_ 16
#define HD_ 64
#define L_ 2
#define E_ 8
#define DFF_ 4096
#define NTOK_ 4096

typedef __attribute__((ext_vector_type(4))) float f32x4;
typedef __attribute__((ext_vector_type(8))) short short8;
typedef __attribute__((ext_vector_type(8))) unsigned short ushort8;

__device__ __forceinline__ unsigned short f2bf(float f) {
  union { float f; unsigned int u; } a; a.f = f;
  unsigned int r = a.u + 0x7FFFu + ((a.u >> 16) & 1u);
  return (unsigned short)(r >> 16);
}

__device__ __forceinline__ void gload_lds16(const void* g, void* l) {
  __builtin_amdgcn_global_load_lds(
      (const __attribute__((address_space(1))) void*)g,
      (__attribute__((address_space(3))) void*)l, 16, 0, 0);
}

// ---------------- LayerNorm: one block per row ----------------
__global__ __launch_bounds__(256)
void ln_kernel(const float* __restrict__ x, const float* __restrict__ w,
               const float* __restrict__ b, float* __restrict__ outf,
               unsigned short* __restrict__ outbf) {
  int row = blockIdx.x;
  int t = threadIdx.x;
  float4 v = ((const float4*)(x + (size_t)row * D_))[t];
  float s  = v.x + v.y + v.z + v.w;
  float s2 = v.x*v.x + v.y*v.y + v.z*v.z + v.w*v.w;
#pragma unroll
  for (int off = 1; off < 64; off <<= 1) {
    s  += __shfl_xor(s, off, 64);
    s2 += __shfl_xor(s2, off, 64);
  }
  __shared__ float red[8];
  int wv_ = t >> 6, ln = t & 63;
  if (ln == 0) { red[wv_*2] = s; red[wv_*2+1] = s2; }
  __syncthreads();
  s  = red[0] + red[2] + red[4] + red[6];
  s2 = red[1] + red[3] + red[5] + red[7];
  float mean = s * (1.0f / D_);
  float var  = s2 * (1.0f / D_) - mean * mean;
  float inv  = 1.0f / sqrtf(var + 1e-5f);
  float4 wv4 = ((const float4*)w)[t];
  float4 bv4 = ((const float4*)b)[t];
  float4 o;
  o.x = (v.x - mean) * inv * wv4.x + bv4.x;
  o.y = (v.y - mean) * inv * wv4.y + bv4.y;
  o.z = (v.z - mean) * inv * wv4.z + bv4.z;
  o.w = (v.w - mean) * inv * wv4.w + bv4.w;
  ((float4*)(outf + (size_t)row * D_))[t] = o;
  ushort4 ob;
  ob.x = f2bf(o.x); ob.y = f2bf(o.y); ob.z = f2bf(o.z); ob.w = f2bf(o.w);
  ((ushort4*)(outbf + (size_t)row * D_))[t] = ob;
}

// ---------------- fp32 GEMM (L0 QKV / WO) ----------------
// C[M][N] = A[M][K] @ W[K][N] + bias.  BM=64 BN=128 BK=16, 256 thr, 4x8 acc.
// mode 0: scatter to (B,H,S,hd) q/k/v (z selects W/bias/out). mode 1: x += C.
__global__ __launch_bounds__(256)
void gemm_f32_kernel(const float* __restrict__ A,
                     const float* __restrict__ W0, const float* __restrict__ W1,
                     const float* __restrict__ W2,
                     const float* __restrict__ bias0, const float* __restrict__ bias1,
                     const float* __restrict__ bias2,
                     float* __restrict__ out0, float* __restrict__ out1,
                     float* __restrict__ out2,
                     int K, int N, int mode, float* __restrict__ xacc) {
  int z = blockIdx.z;
  const float* W    = (z == 0) ? W0 : ((z == 1) ? W1 : W2);
  const float* bias = (z == 0) ? bias0 : ((z == 1) ? bias1 : bias2);
  float* out        = (z == 0) ? out0 : ((z == 1) ? out1 : out2);
  int bx = blockIdx.x, by = blockIdx.y;
  int t = threadIdx.x, tx = t & 15, ty = t >> 4;
  __shared__ float As[2][16][68];
  __shared__ float Bs[2][16][128];
  float acc[4][8];
#pragma unroll
  for (int i = 0; i < 4; ++i)
#pragma unroll
    for (int j = 0; j < 8; ++j) acc[i][j] = 0.f;

  int arow = t >> 2, ak = (t & 3) * 4;
  int bi = t >> 5, bn = (t & 31) * 4;
  const float* Ag = A + (size_t)(by * 64 + arow) * K + ak;
  const float* Bg = W + (size_t)bx * 128 + bn;
  int NT = K / 16;

  float4 ra  = *(const float4*)(Ag);
  float4 rb0 = *(const float4*)(Bg + (size_t)bi * N);
  float4 rb1 = *(const float4*)(Bg + (size_t)(bi + 8) * N);
  As[0][ak+0][arow] = ra.x; As[0][ak+1][arow] = ra.y;
  As[0][ak+2][arow] = ra.z; As[0][ak+3][arow] = ra.w;
  *(float4*)&Bs[0][bi][bn] = rb0; *(float4*)&Bs[0][bi+8][bn] = rb1;
  __syncthreads();
  int buf = 0;
  for (int kt = 0; kt < NT; ++kt) {
    if (kt + 1 < NT) {
      ra  = *(const float4*)(Ag + (kt + 1) * 16);
      rb0 = *(const float4*)(Bg + (size_t)((kt + 1) * 16 + bi) * N);
      rb1 = *(const float4*)(Bg + (size_t)((kt + 1) * 16 + bi + 8) * N);
    }
#pragma unroll
    for (int kk = 0; kk < 16; ++kk) {
      float4 av = *(const float4*)&As[buf][kk][ty * 4];
      float4 b0 = *(const float4*)&Bs[buf][kk][tx * 4];
      float4 b1 = *(const float4*)&Bs[buf][kk][64 + tx * 4];
      float a_[4] = {av.x, av.y, av.z, av.w};
      float b_[8] = {b0.x, b0.y, b0.z, b0.w, b1.x, b1.y, b1.z, b1.w};
#pragma unroll
      for (int i = 0; i < 4; ++i)
#pragma unroll
        for (int j = 0; j < 8; ++j) acc[i][j] += a_[i] * b_[j];
    }
    if (kt + 1 < NT) {
      int nb = buf ^ 1;
      As[nb][ak+0][arow] = ra.x; As[nb][ak+1][arow] = ra.y;
      As[nb][ak+2][arow] = ra.z; As[nb][ak+3][arow] = ra.w;
      *(float4*)&Bs[nb][bi][bn] = rb0; *(float4*)&Bs[nb][bi+8][bn] = rb1;
    }
    __syncthreads();
    buf ^= 1;
  }
#pragma unroll
  for (int i = 0; i < 4; ++i) {
    int row = by * 64 + ty * 4 + i;
#pragma unroll
    for (int half = 0; half < 2; ++half) {
      int col0 = bx * 128 + half * 64 + tx * 4;
      float4 val;
      val.x = acc[i][half*4+0] + bias[col0+0];
      val.y = acc[i][half*4+1] + bias[col0+1];
      val.z = acc[i][half*4+2] + bias[col0+2];
      val.w = acc[i][half*4+3] + bias[col0+3];
      if (mode == 0) {
        int bb = row >> 10, ss = row & 1023, hh = col0 >> 6, dd = col0 & 63;
        *(float4*)&out[(((size_t)(bb * H_ + hh)) * S_ + ss) * HD_ + dd] = val;
      } else {
        float4 old = *(float4*)&xacc[(size_t)row * D_ + col0];
        old.x += val.x; old.y += val.y; old.z += val.z; old.w += val.w;
        *(float4*)&xacc[(size_t)row * D_ + col0] = old;
      }
    }
  }
}

// ---------------- fp32 flash attention ----------------
// block = (qt, h, b); 64 q-rows; online softmax over 64-key tiles; causal.
__global__ __launch_bounds__(256)
void flash_kernel(const float* __restrict__ q, const float* __restrict__ k,
                  const float* __restrict__ v, float* __restrict__ attnout,
                  unsigned short* __restrict__ attnout_bf) {
  int qt = blockIdx.x, hh = blockIdx.y, bb = blockIdx.z;
  int t = threadIdx.x, tx = t & 15, ty = t >> 4;
  __shared__ float Qs[64][65], Ks[64][65], Vs[64][65], Ps[64][65];
  const float* qbase = q + (((size_t)(bb * H_ + hh)) * S_ + qt * 64) * HD_;
  const float* kbase = k + ((size_t)(bb * H_ + hh)) * S_ * HD_;
  const float* vbase = v + ((size_t)(bb * H_ + hh)) * S_ * HD_;
#pragma unroll
  for (int it = 0; it < 4; ++it) {
    int idx = it * 256 + t;
    int r = idx >> 4, c4 = (idx & 15) * 4;
    float4 val = *(const float4*)&qbase[r * 64 + c4];
    Qs[r][c4] = val.x; Qs[r][c4+1] = val.y; Qs[r][c4+2] = val.z; Qs[r][c4+3] = val.w;
  }
  float m_i[4], l_i[4], o[4][4];
#pragma unroll
  for (int i = 0; i < 4; ++i) {
    m_i[i] = -1e30f; l_i[i] = 0.f;
#pragma unroll
    for (int j = 0; j < 4; ++j) o[i][j] = 0.f;
  }
  for (int kt = 0; kt <= qt; ++kt) {
    __syncthreads();
#pragma unroll
    for (int it = 0; it < 4; ++it) {
      int idx = it * 256 + t;
      int r = idx >> 4, c4 = (idx & 15) * 4;
      float4 kv = *(const float4*)&kbase[(size_t)(kt * 64 + r) * 64 + c4];
      Ks[r][c4] = kv.x; Ks[r][c4+1] = kv.y; Ks[r][c4+2] = kv.z; Ks[r][c4+3] = kv.w;
      float4 vv = *(const float4*)&vbase[(size_t)(kt * 64 + r) * 64 + c4];
      Vs[r][c4] = vv.x; Vs[r][c4+1] = vv.y; Vs[r][c4+2] = vv.z; Vs[r][c4+3] = vv.w;
    }
    __syncthreads();
    float sc[4][4];
#pragma unroll
    for (int i = 0; i < 4; ++i)
#pragma unroll
      for (int j = 0; j < 4; ++j) sc[i][j] = 0.f;
#pragma unroll 8
    for (int d = 0; d < 64; ++d) {
      float a0 = Qs[ty*4+0][d], a1 = Qs[ty*4+1][d], a2 = Qs[ty*4+2][d], a3 = Qs[ty*4+3][d];
      float b0 = Ks[tx*4+0][d], b1 = Ks[tx*4+1][d], b2 = Ks[tx*4+2][d], b3 = Ks[tx*4+3][d];
      sc[0][0] += a0*b0; sc[0][1] += a0*b1; sc[0][2] += a0*b2; sc[0][3] += a0*b3;
      sc[1][0] += a1*b0; sc[1][1] += a1*b1; sc[1][2] += a1*b2; sc[1][3] += a1*b3;
      sc[2][0] += a2*b0; sc[2][1] += a2*b1; sc[2][2] += a2*b2; sc[2][3] += a2*b3;
      sc[3][0] += a3*b0; sc[3][1] += a3*b1; sc[3][2] += a3*b2; sc[3][3] += a3*b3;
    }
    bool diag = (kt == qt);
    float rm[4], rs[4], p[4][4];
#pragma unroll
    for (int i = 0; i < 4; ++i) {
#pragma unroll
      for (int j = 0; j < 4; ++j) {
        sc[i][j] *= 0.125f;
        if (diag && (tx * 4 + j) > (ty * 4 + i)) sc[i][j] = -1e30f;
      }
      rm[i] = fmaxf(fmaxf(sc[i][0], sc[i][1]), fmaxf(sc[i][2], sc[i][3]));
    }
#pragma unroll
    for (int off = 1; off < 16; off <<= 1)
#pragma unroll
      for (int i = 0; i < 4; ++i) rm[i] = fmaxf(rm[i], __shfl_xor(rm[i], off, 64));
#pragma unroll
    for (int i = 0; i < 4; ++i) {
      float mn = fmaxf(m_i[i], rm[i]);
      float f = expf(m_i[i] - mn);
      m_i[i] = mn;
#pragma unroll
      for (int j = 0; j < 4; ++j) p[i][j] = expf(sc[i][j] - mn);
      rs[i] = p[i][0] + p[i][1] + p[i][2] + p[i][3];
      l_i[i] = l_i[i] * f;
#pragma unroll
      for (int j = 0; j < 4; ++j) o[i][j] *= f;
    }
#pragma unroll
    for (int off = 1; off < 16; off <<= 1)
#pragma unroll
      for (int i = 0; i < 4; ++i) rs[i] += __shfl_xor(rs[i], off, 64);
#pragma unroll
    for (int i = 0; i < 4; ++i) l_i[i] += rs[i];
#pragma unroll
    for (int i = 0; i < 4; ++i)
#pragma unroll
      for (int j = 0; j < 4; ++j) Ps[ty*4+i][tx*4+j] = p[i][j];
    __syncthreads();
#pragma unroll 8
    for (int kc = 0; kc < 64; ++kc) {
      float p0 = Ps[ty*4+0][kc], p1 = Ps[ty*4+1][kc], p2 = Ps[ty*4+2][kc], p3 = Ps[ty*4+3][kc];
      float v0 = Vs[kc][tx*4+0], v1 = Vs[kc][tx*4+1], v2 = Vs[kc][tx*4+2], v3 = Vs[kc][tx*4+3];
      o[0][0] += p0*v0; o[0][1] += p0*v1; o[0][2] += p0*v2; o[0][3] += p0*v3;
      o[1][0] += p1*v0; o[1][1] += p1*v1; o[1][2] += p1*v2; o[1][3] += p1*v3;
      o[2][0] += p2*v0; o[2][1] += p2*v1; o[2][2] += p2*v2; o[2][3] += p2*v3;
      o[3][0] += p3*v0; o[3][1] += p3*v1; o[3][2] += p3*v2; o[3][3] += p3*v3;
    }
  }
#pragma unroll
  for (int i = 0; i < 4; ++i) {
    float invl = 1.0f / l_i[i];
    size_t srow = (size_t)bb * S_ + qt * 64 + ty * 4 + i;
    int col = hh * 64 + tx * 4;
    float4 val;
    val.x = o[i][0] * invl; val.y = o[i][1] * invl;
    val.z = o[i][2] * invl; val.w = o[i][3] * invl;
    *(float4*)&attnout[srow * D_ + col] = val;
    ushort4 ob;
    ob.x = f2bf(val.x); ob.y = f2bf(val.y); ob.z = f2bf(val.z); ob.w = f2bf(val.w);
    *(ushort4*)&attnout_bf[srow * D_ + col] = ob;
  }
}

// ---------------- gating ----------------
__device__ __forceinline__ void top2_write(const float* lg, float* dst) {
  int i1 = 0;
#pragma unroll
  for (int e = 1; e < E_; ++e) if (lg[e] > lg[i1]) i1 = e;
  int i2 = (i1 == 0) ? 1 : 0;
#pragma unroll
  for (int e = 0; e < E_; ++e) if (e != i1 && lg[e] > lg[i2]) i2 = e;
  float t2 = expf(lg[i2] - lg[i1]);
  float inv = 1.0f / (1.0f + t2);
  float outv[E_];
#pragma unroll
  for (int e = 0; e < E_; ++e) outv[e] = 0.f;
  outv[i1] = inv; outv[i2] = t2 * inv;
#pragma unroll
  for (int e = 0; e < E_; ++e) dst[e] = outv[e];
}

__global__ __launch_bounds__(256)
void gate_token_kernel(const float* __restrict__ h, const float* __restrict__ gw,
                       const float* __restrict__ gb, float* __restrict__ cw) {
  int t = threadIdx.x;
  int w = t >> 6, l = t & 63;
  int tok = blockIdx.x * 4 + w;
  const float* hr = h + (size_t)tok * D_;
  float part[E_];
#pragma unroll
  for (int e = 0; e < E_; ++e) part[e] = 0.f;
  for (int d = l; d < D_; d += 64) {
    float hv = hr[d];
    const float* gr = gw + (size_t)d * E_;
#pragma unroll
    for (int e = 0; e < E_; ++e) part[e] += hv * gr[e];
  }
#pragma unroll
  for (int off = 1; off < 64; off <<= 1)
#pragma unroll
    for (int e = 0; e < E_; ++e) part[e] += __shfl_xor(part[e], off, 64);
  if (l == 0) {
    float lg[E_];
#pragma unroll
    for (int e = 0; e < E_; ++e) lg[e] = part[e] + gb[e];
    top2_write(lg, cw + (size_t)tok * E_);
  }
}

__global__ __launch_bounds__(256)
void gate_seq_kernel(const float* __restrict__ h, const float* __restrict__ gw,
                     const float* __restrict__ gb, float* __restrict__ cw) {
  int bb = blockIdx.x;
  int t = threadIdx.x;
  const float* hb = h + (size_t)bb * S_ * D_;
  float acc[4] = {0.f, 0.f, 0.f, 0.f};
  for (int s = 0; s < S_; ++s) {
#pragma unroll
    for (int u = 0; u < 4; ++u) acc[u] += hb[(size_t)s * D_ + u * 256 + t];
  }
  __shared__ float hm[D_];
#pragma unroll
  for (int u = 0; u < 4; ++u) hm[u * 256 + t] = acc[u] * (1.0f / S_);
  __syncthreads();
  if (t < 64) {
    float part[E_];
#pragma unroll
    for (int e = 0; e < E_; ++e) part[e] = 0.f;
    for (int d = t; d < D_; d += 64) {
      float hv = hm[d];
#pragma unroll
      for (int e = 0; e < E_; ++e) part[e] += hv * gw[(size_t)d * E_ + e];
    }
#pragma unroll
    for (int off = 1; off < 64; off <<= 1)
#pragma unroll
      for (int e = 0; e < E_; ++e) part[e] += __shfl_xor(part[e], off, 64);
    if (t == 0) {
      float lg[E_];
#pragma unroll
      for (int e = 0; e < E_; ++e) lg[e] = part[e] + gb[e];
      top2_write(lg, cw + (size_t)bb * E_);
    }
  }
}

// ---------------- transpose + cast: in f32 [R][C] -> out bf16 [C][R] ----------------
__global__ __launch_bounds__(256)
void transpose_cast_kernel(const float* __restrict__ in, unsigned short* __restrict__ out,
                           int R, int C) {
  __shared__ float tile[64][68];
  int c0 = blockIdx.x * 64, r0 = blockIdx.y * 64;
  int t = threadIdx.x;
#pragma unroll
  for (int it = 0; it < 4; ++it) {
    int idx = it * 256 + t;
    int r = idx >> 4, c4 = (idx & 15) * 4;
    float4 v4 = *(const float4*)&in[(size_t)(r0 + r) * C + c0 + c4];
    *(float4*)&tile[r][c4] = v4;
  }
  __syncthreads();
#pragma unroll
  for (int it = 0; it < 2; ++it) {
    int idx = it * 256 + t;
    int c = idx >> 3, r8 = (idx & 7) * 8;
    ushort8 p;
#pragma unroll
    for (int u = 0; u < 8; ++u) p[u] = f2bf(tile[r8 + u][c]);
    *(ushort8*)&out[(size_t)(c0 + c) * R + r0 + r8] = p;
  }
}

// ---------------- bf16 MFMA GEMM ----------------
// C[M][N] = A[M][K](bf16) @ BT[N][K](bf16)^T.  128x128 tile, BK=32, 4 waves.
// MODE 0: gelu(C+bias)->bf16 outbf.  MODE 1: xacc += (C+bias)*cw[row>>shift][e].
// MODE 2: C+bias scattered to (B,H,S,hd) outf.  MODE 3: xacc += C+bias.
template<int MODE>
__global__ __launch_bounds__(256)
void gemm_bf16_kernel(const unsigned short* __restrict__ A,
                      const unsigned short* __restrict__ BT, int K,
                      const float* __restrict__ bias,
                      float* __restrict__ outf, unsigned short* __restrict__ outbf,
                      int N, const float* __restrict__ cw, int row_shift, int e,
                      float* __restrict__ xacc) {
  __shared__ unsigned short As[2][128 * 32];
  __shared__ unsigned short Bs[2][128 * 32];
  int t = threadIdx.x;
  int w = t >> 6, l = t & 63;
  int bx = blockIdx.x, by = blockIdx.y;
  const unsigned short* Ag = A + (size_t)by * 128 * K;
  const unsigned short* Bg = BT + (size_t)bx * 128 * K;
  int ch0 = w * 64 + l;
  int r0s = ch0 >> 2, k0s = (ch0 & 3) * 8;
  int ch1 = 256 + ch0;
  int r1s = ch1 >> 2, k1s = (ch1 & 3) * 8;

  f32x4 acc[4][4];
  f32x4 zf = {0.f, 0.f, 0.f, 0.f};
#pragma unroll
  for (int m = 0; m < 4; ++m)
#pragma unroll
    for (int n = 0; n < 4; ++n) acc[m][n] = zf;

  int NT = K >> 5;
  // prologue stage tile 0 -> buf 0
  {
    const unsigned short* ag = Ag;
    const unsigned short* bg = Bg;
    gload_lds16(ag + (size_t)r0s * K + k0s, &As[0][w * 512]);
    gload_lds16(ag + (size_t)r1s * K + k1s, &As[0][2048 + w * 512]);
    gload_lds16(bg + (size_t)r0s * K + k0s, &Bs[0][w * 512]);
    gload_lds16(bg + (size_t)r1s * K + k1s, &Bs[0][2048 + w * 512]);
  }
  __syncthreads();
  int buf = 0;
  int wm = w >> 1, wn = w & 1;
  int lr = l & 15, kg = (l >> 4) * 8;
  for (int kt = 0; kt < NT; ++kt) {
    if (kt + 1 < NT) {
      const unsigned short* ag = Ag + (size_t)(kt + 1) * 32;
      const unsigned short* bg = Bg + (size_t)(kt + 1) * 32;
      int nb = buf ^ 1;
      gload_lds16(ag + (size_t)r0s * K + k0s, &As[nb][w * 512]);
      gload_lds16(ag + (size_t)r1s * K + k1s, &As[nb][2048 + w * 512]);
      gload_lds16(bg + (size_t)r0s * K + k0s, &Bs[nb][w * 512]);
      gload_lds16(bg + (size_t)r1s * K + k1s, &Bs[nb][2048 + w * 512]);
    }
    short8 a[4], b[4];
#pragma unroll
    for (int m = 0; m < 4; ++m)
      a[m] = *(const short8*)&As[buf][(wm * 64 + m * 16 + lr) * 32 + kg];
#pragma unroll
    for (int n = 0; n < 4; ++n)
      b[n] = *(const short8*)&Bs[buf][(wn * 64 + n * 16 + lr) * 32 + kg];
#pragma unroll
    for (int m = 0; m < 4; ++m)
#pragma unroll
      for (int n = 0; n < 4; ++n)
        acc[m][n] = __builtin_amdgcn_mfma_f32_16x16x32_bf16(a[m], b[n], acc[m][n], 0, 0, 0);
    __syncthreads();
    buf ^= 1;
  }
  int gr0 = by * 128 + wm * 64, gc0 = bx * 128 + wn * 64;
#pragma unroll
  for (int n = 0; n < 4; ++n) {
    int col = gc0 + n * 16 + lr;
    float bia = bias[col];
#pragma unroll
    for (int m = 0; m < 4; ++m) {
#pragma unroll
      for (int j = 0; j < 4; ++j) {
        int row = gr0 + m * 16 + (l >> 4) * 4 + j;
        float val = acc[m][n][j] + bia;
        if (MODE == 0) {
          float g = 0.5f * val * (1.0f + erff(val * 0.70710678118654752f));
          outbf[(size_t)row * N + col] = f2bf(g);
        } else if (MODE == 1) {
          float wgt = cw[(size_t)(row >> row_shift) * E_ + e];
          xacc[(size_t)row * D_ + col] += val * wgt;
        } else if (MODE == 2) {
          int bb = row >> 10, ss = row & 1023, hh = col >> 6, dd = col & 63;
          outf[(((size_t)(bb * H_ + hh)) * S_ + ss) * HD_ + dd] = val;
        } else {
          xacc[(size_t)row * D_ + col] += val;
        }
      }
    }
  }
}

// ---------------- host ----------------
extern "C" void kernel_launch(void* const* d_in, const int* in_sizes, int n_in,
                              void* d_out, int out_size, void* d_ws, size_t ws_size,
                              hipStream_t stream) {
  (void)in_sizes; (void)n_in; (void)out_size;
  const float* x_in   = (const float*)d_in[0];
  const float* ln1_w  = (const float*)d_in[1];
  const float* ln1_b  = (const float*)d_in[2];
  const float* ln2_w  = (const float*)d_in[3];
  const float* ln2_b  = (const float*)d_in[4];
  const float* wq     = (const float*)d_in[5];
  const float* wk     = (const float*)d_in[6];
  const float* wv     = (const float*)d_in[7];
  const float* wo     = (const float*)d_in[8];
  const float* bq     = (const float*)d_in[9];
  const float* bk     = (const float*)d_in[10];
  const float* bv     = (const float*)d_in[11];
  const float* bo     = (const float*)d_in[12];
  const float* gate_w = (const float*)d_in[13];
  const float* gate_b = (const float*)d_in[14];
  const float* e_w1   = (const float*)d_in[15];
  const float* e_b1   = (const float*)d_in[16];
  const float* e_w2   = (const float*)d_in[17];
  const float* e_b2   = (const float*)d_in[18];
  float* x = (float*)d_out;

  char* ws = (char*)d_ws;
  size_t off = 0;
  auto alloc = [&](size_t bytes) -> void* {
    void* p = ws + off; off += (bytes + 255) & ~(size_t)255; return p;
  };
  float* h              = (float*)alloc((size_t)NTOK_ * D_ * 4);
  unsigned short* h_bf  = (unsigned short*)alloc((size_t)NTOK_ * D_ * 2);
  float* qb             = (float*)alloc((size_t)NTOK_ * D_ * 4);
  float* kb             = (float*)alloc((size_t)NTOK_ * D_ * 4);
  float* vb             = (float*)alloc((size_t)NTOK_ * D_ * 4);
  float* attno          = (float*)alloc((size_t)NTOK_ * D_ * 4);
  unsigned short* attno_bf = (unsigned short*)alloc((size_t)NTOK_ * D_ * 2);
  unsigned short* t1_bf = (unsigned short*)alloc((size_t)NTOK_ * DFF_ * 2);
  unsigned short* wT1   = (unsigned short*)alloc((size_t)D_ * DFF_ * 2);
  unsigned short* wT2   = (unsigned short*)alloc((size_t)D_ * DFF_ * 2);
  unsigned short* wTat  = (unsigned short*)alloc((size_t)4 * D_ * D_ * 2);
  float* cw_tok         = (float*)alloc((size_t)NTOK_ * E_ * 4);
  float* cw_seq         = (float*)alloc((size_t)B_ * E_ * 4);
  if (off > ws_size) return;  // workspace too small; fail loudly via poison output

  hipMemcpyAsync(x, x_in, (size_t)NTOK_ * D_ * 4, hipMemcpyDeviceToDevice, stream);

  for (int l = 0; l < L_; ++l) {
    const float* wq_l = wq + (size_t)l * D_ * D_;
    const float* wk_l = wk + (size_t)l * D_ * D_;
    const float* wv_l = wv + (size_t)l * D_ * D_;
    const float* wo_l = wo + (size_t)l * D_ * D_;
    const float* bq_l = bq + (size_t)l * D_;
    const float* bk_l = bk + (size_t)l * D_;
    const float* bv_l = bv + (size_t)l * D_;
    const float* bo_l = bo + (size_t)l * D_;
    const float* gw_l = gate_w + (size_t)l * D_ * E_;
    const float* gb_l = gate_b + (size_t)l * E_;

    ln_kernel<<<NTOK_, 256, 0, stream>>>(x, ln1_w + (size_t)l * D_, ln1_b + (size_t)l * D_, h, h_bf);

    if (l == 0) {
      // fp32 QKV (gate-decision-critical path must be fp32-accurate)
      gemm_f32_kernel<<<dim3(D_ / 128, NTOK_ / 64, 3), 256, 0, stream>>>(
          h, wq_l, wk_l, wv_l, bq_l, bk_l, bv_l, qb, kb, vb, D_, D_, 0, nullptr);
    } else {
      transpose_cast_kernel<<<dim3(D_ / 64, D_ / 64), 256, 0, stream>>>(wq_l, wTat + 0 * (size_t)D_ * D_, D_, D_);
      transpose_cast_kernel<<<dim3(D_ / 64, D_ / 64), 256, 0, stream>>>(wk_l, wTat + 1 * (size_t)D_ * D_, D_, D_);
      transpose_cast_kernel<<<dim3(D_ / 64, D_ / 64), 256, 0, stream>>>(wv_l, wTat + 2 * (size_t)D_ * D_, D_, D_);
      transpose_cast_kernel<<<dim3(D_ / 64, D_ / 64), 256, 0, stream>>>(wo_l, wTat + 3 * (size_t)D_ * D_, D_, D_);
      gemm_bf16_kernel<2><<<dim3(D_ / 128, NTOK_ / 128), 256, 0, stream>>>(
          h_bf, wTat + 0 * (size_t)D_ * D_, D_, bq_l, qb, nullptr, D_, nullptr, 0, 0, nullptr);
      gemm_bf16_kernel<2><<<dim3(D_ / 128, NTOK_ / 128), 256, 0, stream>>>(
          h_bf, wTat + 1 * (size_t)D_ * D_, D_, bk_l, kb, nullptr, D_, nullptr, 0, 0, nullptr);
      gemm_bf16_kernel<2><<<dim3(D_ / 128, NTOK_ / 128), 256, 0, stream>>>(
          h_bf, wTat + 2 * (size_t)D_ * D_, D_, bv_l, vb, nullptr, D_, nullptr, 0, 0, nullptr);
    }

    flash_kernel<<<dim3(S_ / 64, H_, B_), 256, 0, stream>>>(qb, kb, vb, attno, attno_bf);

    if (l == 0) {
      gemm_f32_kernel<<<dim3(D_ / 128, NTOK_ / 64, 1), 256, 0, stream>>>(
          attno, wo_l, nullptr, nullptr, bo_l, nullptr, nullptr,
          nullptr, nullptr, nullptr, D_, D_, 1, x);
    } else {
      gemm_bf16_kernel<3><<<dim3(D_ / 128, NTOK_ / 128), 256, 0, stream>>>(
          attno_bf, wTat + 3 * (size_t)D_ * D_, D_, bo_l, nullptr, nullptr, D_, nullptr, 0, 0, x);
    }

    ln_kernel<<<NTOK_, 256, 0, stream>>>(x, ln2_w + (size_t)l * D_, ln2_b + (size_t)l * D_, h, h_bf);

    if (l == 0) {
      gate_token_kernel<<<NTOK_ / 4, 256, 0, stream>>>(h, gw_l, gb_l, cw_tok);
    } else {
      gate_seq_kernel<<<B_, 256, 0, stream>>>(h, gw_l, gb_l, cw_seq);
    }
    const float* cwp = (l == 0) ? cw_tok : cw_seq;
    int shift = (l == 0) ? 0 : 10;

    for (int ee = 0; ee < E_; ++ee) {
      const float* w1e = e_w1 + ((size_t)l * E_ + ee) * D_ * DFF_;
      const float* b1e = e_b1 + ((size_t)l * E_ + ee) * DFF_;
      const float* w2e = e_w2 + ((size_t)l * E_ + ee) * DFF_ * D_;
      const float* b2e = e_b2 + ((size_t)l * E_ + ee) * D_;
      transpose_cast_kernel<<<dim3(DFF_ / 64, D_ / 64), 256, 0, stream>>>(w1e, wT1, D_, DFF_);
      gemm_bf16_kernel<0><<<dim3(DFF_ / 128, NTOK_ / 128), 256, 0, stream>>>(
          h_bf, wT1, D_, b1e, nullptr, t1_bf, DFF_, nullptr, 0, 0, nullptr);
      transpose_cast_kernel<<<dim3(D_ / 64, DFF_ / 64), 256, 0, stream>>>(w2e, wT2, DFF_, D_);
      gemm_bf16_kernel<1><<<dim3(D_ / 128, NTOK_ / 128), 256, 0, stream>>>(
          t1_bf, wT2, DFF_, b2e, nullptr, nullptr, D_, cwp, shift, ee, x);
    }
  }
}